// Round 10
// baseline (227.790 us; speedup 1.0000x reference)
//
#include <hip/hip_runtime.h>

#define LOG2E 1.44269504088896340736f

__device__ __forceinline__ float fast_exp2(float x) {
#if __has_builtin(__builtin_amdgcn_exp2f)
    return __builtin_amdgcn_exp2f(x);
#else
    return exp2f(x);
#endif
}

constexpr int BATCH = 32;
constexpr int CH = 3;
constexpr int KPAL = 32;
constexpr int PIX_PER_BATCH = 256 * 256;            // 65536
constexpr int THREADS = 256;
constexpr int PIX_PER_THREAD = 4;
constexpr int BLOCKS_PER_BATCH = PIX_PER_BATCH / (THREADS * PIX_PER_THREAD);  // 64
constexpr int NBLOCKS = BATCH * BLOCKS_PER_BATCH;   // 2048

// ROUND-10: MEASUREMENT ROUND. Kernel body is byte-identical to Round 9
// (known-good: no spill, VGPR-relaxed, 4 px/thread). kernel_launch issues it
// 8x back-to-back on the stream. dur_us ≈ harness_overhead + 8*k decomposes
// the ~60 us of in-window harness work (poison fills + input restore,
// inferred from R3/R8: dur_us - kernel_row ≈ 57-65 us) from true kernel
// time k. R9 single-launch baseline: 90.6 us.
__global__ __launch_bounds__(THREADS, 4)
void palette_quant_kernel(const float* __restrict__ images,
                          const float* __restrict__ palettes,
                          const float* __restrict__ temp,
                          float* __restrict__ out)
{
    __shared__ float4 ab[KPAL];   // (a0, a1, a2, b) per palette entry
    __shared__ float s_fs;        // final-scale constant T/(2*log2e)

    const int batch = blockIdx.x >> 6;   // / BLOCKS_PER_BATCH

    if (threadIdx.x < KPAL) {
        const float T = *temp;
        const float cinv = LOG2E / T;
        const float* p = palettes + (batch * KPAL + threadIdx.x) * CH;
        const float p0 = p[0], p1 = p[1], p2 = p[2];
        const float b = -(p0 * p0 + p1 * p1 + p2 * p2) * cinv;
        const float c2 = 2.0f * cinv;
        ab[threadIdx.x] = make_float4(p0 * c2, p1 * c2, p2 * c2, b);
        if (threadIdx.x == 0) s_fs = T * (0.5f / LOG2E);
    }
    __syncthreads();

    const int tid = ((blockIdx.x & 63) << 8) | threadIdx.x;  // 0..16383 within batch
    const long long base = (long long)batch * (PIX_PER_BATCH * CH)
                         + (long long)tid * (PIX_PER_THREAD * CH);

    const float4* ip = reinterpret_cast<const float4*>(images + base);
    const float4 v0 = ip[0];
    const float4 v1 = ip[1];
    const float4 v2 = ip[2];

    // De-interleave 4 pixels' RGB into NAMED scalars (no arrays!).
    const float xA0 = v0.x, xA1 = v0.y, xA2 = v0.z;
    const float xB0 = v0.w, xB1 = v1.x, xB2 = v1.y;
    const float xC0 = v1.z, xC1 = v1.w, xC2 = v2.x;
    const float xD0 = v2.y, xD1 = v2.z, xD2 = v2.w;

    float sumA = 0.f, oA0 = 0.f, oA1 = 0.f, oA2 = 0.f;
    float sumB = 0.f, oB0 = 0.f, oB1 = 0.f, oB2 = 0.f;
    float sumC = 0.f, oC0 = 0.f, oC1 = 0.f, oC2 = 0.f;
    float sumD = 0.f, oD0 = 0.f, oD1 = 0.f, oD2 = 0.f;

#define PIX_STEP(X0, X1, X2, SUM, O0, O1, O2)                 \
    {                                                         \
        float s = fmaf((X0), a.x, a.w);                       \
        s = fmaf((X1), a.y, s);                               \
        s = fmaf((X2), a.z, s);                               \
        const float w = fast_exp2(s);                         \
        (SUM) += w;                                           \
        (O0) = fmaf(w, a.x, (O0));                            \
        (O1) = fmaf(w, a.y, (O1));                            \
        (O2) = fmaf(w, a.z, (O2));                            \
    }

#pragma unroll
    for (int k = 0; k < KPAL; ++k) {
        const float4 a = ab[k];   // uniform addr -> one ds_read_b128 broadcast per k
        PIX_STEP(xA0, xA1, xA2, sumA, oA0, oA1, oA2)
        PIX_STEP(xB0, xB1, xB2, sumB, oB0, oB1, oB2)
        PIX_STEP(xC0, xC1, xC2, sumC, oC0, oC1, oC2)
        PIX_STEP(xD0, xD1, xD2, sumD, oD0, oD1, oD2)
    }
#undef PIX_STEP

    const float fs = s_fs;
    const float rA = fs * __builtin_amdgcn_rcpf(sumA);
    const float rB = fs * __builtin_amdgcn_rcpf(sumB);
    const float rC = fs * __builtin_amdgcn_rcpf(sumC);
    const float rD = fs * __builtin_amdgcn_rcpf(sumD);

    const float4 w0 = make_float4(oA0 * rA, oA1 * rA, oA2 * rA, oB0 * rB);
    const float4 w1 = make_float4(oB1 * rB, oB2 * rB, oC0 * rC, oC1 * rC);
    const float4 w2 = make_float4(oC2 * rC, oD0 * rD, oD1 * rD, oD2 * rD);

    float4* op = reinterpret_cast<float4*>(out + base);
    op[0] = w0;
    op[1] = w1;
    op[2] = w2;
}

extern "C" void kernel_launch(void* const* d_in, const int* in_sizes, int n_in,
                              void* d_out, int out_size, void* d_ws, size_t ws_size,
                              hipStream_t stream) {
    const float* images   = (const float*)d_in[0];
    const float* palettes = (const float*)d_in[1];
    const float* temp     = (const float*)d_in[2];
    float* out            = (float*)d_out;

    // 8 identical launches: dur_us = overhead + 8*k. Same work every call
    // (each launch recomputes the same output from the same input).
    for (int rep = 0; rep < 8; ++rep) {
        palette_quant_kernel<<<dim3(NBLOCKS), dim3(THREADS), 0, stream>>>(
            images, palettes, temp, out);
    }
}

// Round 11
// 134.929 us; speedup vs baseline: 1.6882x; 1.6882x over previous
//
#include <hip/hip_runtime.h>

#define LOG2E 1.44269504088896340736f

__device__ __forceinline__ float fast_exp2(float x) {
#if __has_builtin(__builtin_amdgcn_exp2f)
    return __builtin_amdgcn_exp2f(x);
#else
    return exp2f(x);
#endif
}

constexpr int BATCH = 32;
constexpr int CH = 3;
constexpr int KPAL = 32;
constexpr int PIX_PER_BATCH = 256 * 256;            // 65536
constexpr int THREADS = 256;
constexpr int PIX_PER_THREAD = 4;
constexpr int BLOCKS_PER_BATCH = PIX_PER_BATCH / (THREADS * PIX_PER_THREAD);  // 64
constexpr int NBLOCKS = BATCH * BLOCKS_PER_BATCH;   // 2048

// ROUND-11: DIAGNOSTIC ROUND. Round-9/10 decomposition gave true kernel time
// k ~= 19.6 us vs a ~10 us static issue model — cause of the 2x gap unknown,
// and the kernel's counter row is invisible (below the 44 us harness fills).
// This round repeats the COMPUTE phase 4x in-kernel behind asm opacity
// barriers (loads/stores once, identical output) so the dispatch runs
// ~75-80 us and surfaces VALUBusy / Occupancy / VGPR / FETCH in the top-5.
// Discriminator: VALUBusy >=75% -> issue-bound (next: packed f32 math);
// <=55% -> latency-bound (next: s_load palette / more ILP).
__global__ __launch_bounds__(THREADS, 4)
void palette_quant_kernel(const float* __restrict__ images,
                          const float* __restrict__ palettes,
                          const float* __restrict__ temp,
                          float* __restrict__ out)
{
    __shared__ float4 ab[KPAL];   // (a0, a1, a2, b) per palette entry
    __shared__ float s_fs;        // final-scale constant T/(2*log2e)

    const int batch = blockIdx.x >> 6;   // / BLOCKS_PER_BATCH

    if (threadIdx.x < KPAL) {
        const float T = *temp;
        const float cinv = LOG2E / T;
        const float* p = palettes + (batch * KPAL + threadIdx.x) * CH;
        const float p0 = p[0], p1 = p[1], p2 = p[2];
        const float b = -(p0 * p0 + p1 * p1 + p2 * p2) * cinv;
        const float c2 = 2.0f * cinv;
        ab[threadIdx.x] = make_float4(p0 * c2, p1 * c2, p2 * c2, b);
        if (threadIdx.x == 0) s_fs = T * (0.5f / LOG2E);
    }
    __syncthreads();

    const int tid = ((blockIdx.x & 63) << 8) | threadIdx.x;  // 0..16383 within batch
    const long long base = (long long)batch * (PIX_PER_BATCH * CH)
                         + (long long)tid * (PIX_PER_THREAD * CH);

    const float4* ip = reinterpret_cast<const float4*>(images + base);
    const float4 v0 = ip[0];
    const float4 v1 = ip[1];
    const float4 v2 = ip[2];

    // De-interleave 4 pixels' RGB into NAMED scalars (mutable: asm-opaqued).
    float xA0 = v0.x, xA1 = v0.y, xA2 = v0.z;
    float xB0 = v0.w, xB1 = v1.x, xB2 = v1.y;
    float xC0 = v1.z, xC1 = v1.w, xC2 = v2.x;
    float xD0 = v2.y, xD1 = v2.z, xD2 = v2.w;

    float sumA, oA0, oA1, oA2;
    float sumB, oB0, oB1, oB2;
    float sumC, oC0, oC1, oC2;
    float sumD, oD0, oD1, oD2;

#define PIX_STEP(X0, X1, X2, SUM, O0, O1, O2)                 \
    {                                                         \
        float s = fmaf((X0), a.x, a.w);                       \
        s = fmaf((X1), a.y, s);                               \
        s = fmaf((X2), a.z, s);                               \
        const float w = fast_exp2(s);                         \
        (SUM) += w;                                           \
        (O0) = fmaf(w, a.x, (O0));                            \
        (O1) = fmaf(w, a.y, (O1));                            \
        (O2) = fmaf(w, a.z, (O2));                            \
    }

    for (int rep = 0; rep < 4; ++rep) {
        // Opacity barrier: marks the 12 inputs "modified" so each rep's
        // compute is a fresh computation (defeats CSE across reps). Values
        // are in fact unchanged -> math identical to the real kernel.
        asm volatile("" : "+v"(xA0), "+v"(xA1), "+v"(xA2),
                          "+v"(xB0), "+v"(xB1), "+v"(xB2),
                          "+v"(xC0), "+v"(xC1), "+v"(xC2),
                          "+v"(xD0), "+v"(xD1), "+v"(xD2));
        sumA = 0.f; oA0 = 0.f; oA1 = 0.f; oA2 = 0.f;
        sumB = 0.f; oB0 = 0.f; oB1 = 0.f; oB2 = 0.f;
        sumC = 0.f; oC0 = 0.f; oC1 = 0.f; oC2 = 0.f;
        sumD = 0.f; oD0 = 0.f; oD1 = 0.f; oD2 = 0.f;

#pragma unroll
        for (int k = 0; k < KPAL; ++k) {
            const float4 a = ab[k];   // uniform addr -> ds_read_b128 broadcast
            PIX_STEP(xA0, xA1, xA2, sumA, oA0, oA1, oA2)
            PIX_STEP(xB0, xB1, xB2, sumB, oB0, oB1, oB2)
            PIX_STEP(xC0, xC1, xC2, sumC, oC0, oC1, oC2)
            PIX_STEP(xD0, xD1, xD2, sumD, oD0, oD1, oD2)
        }

        // Sink: keep every rep's results live (no DCE of reps 0..2).
        asm volatile("" :: "v"(sumA), "v"(oA0), "v"(oA1), "v"(oA2),
                           "v"(sumB), "v"(oB0), "v"(oB1), "v"(oB2),
                           "v"(sumC), "v"(oC0), "v"(oC1), "v"(oC2),
                           "v"(sumD), "v"(oD0), "v"(oD1), "v"(oD2));
    }
#undef PIX_STEP

    const float fs = s_fs;
    const float rA = fs * __builtin_amdgcn_rcpf(sumA);
    const float rB = fs * __builtin_amdgcn_rcpf(sumB);
    const float rC = fs * __builtin_amdgcn_rcpf(sumC);
    const float rD = fs * __builtin_amdgcn_rcpf(sumD);

    const float4 w0 = make_float4(oA0 * rA, oA1 * rA, oA2 * rA, oB0 * rB);
    const float4 w1 = make_float4(oB1 * rB, oB2 * rB, oC0 * rC, oC1 * rC);
    const float4 w2 = make_float4(oC2 * rC, oD0 * rD, oD1 * rD, oD2 * rD);

    float4* op = reinterpret_cast<float4*>(out + base);
    op[0] = w0;
    op[1] = w1;
    op[2] = w2;
}

extern "C" void kernel_launch(void* const* d_in, const int* in_sizes, int n_in,
                              void* d_out, int out_size, void* d_ws, size_t ws_size,
                              hipStream_t stream) {
    const float* images   = (const float*)d_in[0];
    const float* palettes = (const float*)d_in[1];
    const float* temp     = (const float*)d_in[2];
    float* out            = (float*)d_out;

    palette_quant_kernel<<<dim3(NBLOCKS), dim3(THREADS), 0, stream>>>(
        images, palettes, temp, out);
}

// Round 12
// 88.284 us; speedup vs baseline: 2.5802x; 1.5284x over previous
//
#include <hip/hip_runtime.h>

#define LOG2E 1.44269504088896340736f

typedef float v2f __attribute__((ext_vector_type(2)));

__device__ __forceinline__ float fast_exp2(float x) {
#if __has_builtin(__builtin_amdgcn_exp2f)
    return __builtin_amdgcn_exp2f(x);
#else
    return exp2f(x);
#endif
}

constexpr int BATCH = 32;
constexpr int CH = 3;
constexpr int KPAL = 32;
constexpr int NPAIR = KPAL / 2;                      // 16 k-pairs
constexpr int PIX_PER_BATCH = 256 * 256;             // 65536
constexpr int THREADS = 256;
constexpr int PIX_PER_THREAD = 2;
constexpr int BLOCKS_PER_BATCH = PIX_PER_BATCH / (THREADS * PIX_PER_THREAD);  // 128
constexpr int NBLOCKS = BATCH * BLOCKS_PER_BATCH;    // 4096
constexpr int COEFF_PER_BATCH = NPAIR * 8;           // 128 floats

// ROUND-12: Round-11 diagnostic showed VALUBusy~80% (issue-bound) with
// scalar v_fma_f32 — which runs at HALF the chip's fp32 rate (157.3 TF spec
// requires v_pk_fma_f32). This round: (1) packed f32 math over k-PAIRS so
// pixel splats hoist out of the loop; (2) palette coeffs precomputed
// pair-interleaved into d_ws by a tiny setup kernel and read via
// wave-uniform loads (s_load path, scalar cache) — LDS eliminated, no lgkm
// stalls; (3) 2 px/thread -> 4096 blocks (2x TLP vs R9).

// Setup: 512 threads total; thread t -> (batch, pair j). Writes
// {a0e,a0o, a1e,a1o, a2e,a2o, be,bo} where aXe/aXo are the even/odd-k
// pre-scaled coeffs aX = 2*log2e/T * pX, b = -|p|^2*log2e/T.
__global__ void palette_coeff_kernel(const float* __restrict__ palettes,
                                     const float* __restrict__ temp,
                                     float* __restrict__ ws)
{
    const int t = blockIdx.x * blockDim.x + threadIdx.x;
    if (t >= BATCH * NPAIR) return;
    const int batch = t >> 4;
    const int j = t & (NPAIR - 1);

    const float T = *temp;
    const float cinv = LOG2E / T;
    const float c2 = 2.0f * cinv;

    const float* p = palettes + batch * KPAL * CH + (2 * j) * CH;
    const float e0 = p[0], e1 = p[1], e2 = p[2];   // k = 2j
    const float f0 = p[3], f1 = p[4], f2 = p[5];   // k = 2j+1

    float* w = ws + batch * COEFF_PER_BATCH + j * 8;
    w[0] = e0 * c2;  w[1] = f0 * c2;
    w[2] = e1 * c2;  w[3] = f1 * c2;
    w[4] = e2 * c2;  w[5] = f2 * c2;
    w[6] = -(e0 * e0 + e1 * e1 + e2 * e2) * cinv;
    w[7] = -(f0 * f0 + f1 * f1 + f2 * f2) * cinv;
}

__global__ __launch_bounds__(THREADS, 4)
void palette_quant_kernel(const float* __restrict__ images,
                          const float* __restrict__ coeffs,
                          const float* __restrict__ temp,
                          float* __restrict__ out)
{
    const int batch = blockIdx.x >> 7;               // 128 blocks per batch
    const float* cb = coeffs + batch * COEFF_PER_BATCH;  // wave-uniform

    const long long pp   = (long long)blockIdx.x * THREADS + threadIdx.x;
    const long long base = pp * (PIX_PER_THREAD * CH);   // *6, 8B-aligned

    const v2f v0 = *reinterpret_cast<const v2f*>(images + base);
    const v2f v1 = *reinterpret_cast<const v2f*>(images + base + 2);
    const v2f v2_ = *reinterpret_cast<const v2f*>(images + base + 4);

    // Pixel A = (v0.x, v0.y, v1.x); pixel B = (v1.y, v2_.x, v2_.y).
    // Splat each channel ONCE (outside the k loop) for packed use.
    const v2f XA0 = {v0.x, v0.x}, XA1 = {v0.y, v0.y}, XA2 = {v1.x, v1.x};
    const v2f XB0 = {v1.y, v1.y}, XB1 = {v2_.x, v2_.x}, XB2 = {v2_.y, v2_.y};

    v2f sumA = {0.f, 0.f}, oA0 = {0.f, 0.f}, oA1 = {0.f, 0.f}, oA2 = {0.f, 0.f};
    v2f sumB = {0.f, 0.f}, oB0 = {0.f, 0.f}, oB1 = {0.f, 0.f}, oB2 = {0.f, 0.f};

#pragma unroll
    for (int j = 0; j < NPAIR; ++j) {
        const v2f A0 = *reinterpret_cast<const v2f*>(cb + 8 * j + 0);
        const v2f A1 = *reinterpret_cast<const v2f*>(cb + 8 * j + 2);
        const v2f A2 = *reinterpret_cast<const v2f*>(cb + 8 * j + 4);
        const v2f Bb = *reinterpret_cast<const v2f*>(cb + 8 * j + 6);
        {
            v2f s = __builtin_elementwise_fma(XA0, A0, Bb);
            s = __builtin_elementwise_fma(XA1, A1, s);
            s = __builtin_elementwise_fma(XA2, A2, s);
            v2f w; w.x = fast_exp2(s.x); w.y = fast_exp2(s.y);
            sumA += w;                                    // v_pk_add_f32
            oA0 = __builtin_elementwise_fma(w, A0, oA0);
            oA1 = __builtin_elementwise_fma(w, A1, oA1);
            oA2 = __builtin_elementwise_fma(w, A2, oA2);
        }
        {
            v2f s = __builtin_elementwise_fma(XB0, A0, Bb);
            s = __builtin_elementwise_fma(XB1, A1, s);
            s = __builtin_elementwise_fma(XB2, A2, s);
            v2f w; w.x = fast_exp2(s.x); w.y = fast_exp2(s.y);
            sumB += w;
            oB0 = __builtin_elementwise_fma(w, A0, oB0);
            oB1 = __builtin_elementwise_fma(w, A1, oB1);
            oB2 = __builtin_elementwise_fma(w, A2, oB2);
        }
    }

    const float T = *temp;                   // wave-uniform -> s_load
    const float fs = T * (0.5f / LOG2E);
    const float rA = fs * __builtin_amdgcn_rcpf(sumA.x + sumA.y);
    const float rB = fs * __builtin_amdgcn_rcpf(sumB.x + sumB.y);

    const v2f w0 = {(oA0.x + oA0.y) * rA, (oA1.x + oA1.y) * rA};
    const v2f w1 = {(oA2.x + oA2.y) * rA, (oB0.x + oB0.y) * rB};
    const v2f w2 = {(oB1.x + oB1.y) * rB, (oB2.x + oB2.y) * rB};

    *reinterpret_cast<v2f*>(out + base)     = w0;
    *reinterpret_cast<v2f*>(out + base + 2) = w1;
    *reinterpret_cast<v2f*>(out + base + 4) = w2;
}

extern "C" void kernel_launch(void* const* d_in, const int* in_sizes, int n_in,
                              void* d_out, int out_size, void* d_ws, size_t ws_size,
                              hipStream_t stream) {
    const float* images   = (const float*)d_in[0];
    const float* palettes = (const float*)d_in[1];
    const float* temp     = (const float*)d_in[2];
    float* out            = (float*)d_out;
    float* ws             = (float*)d_ws;   // needs 32*128*4 = 16 KB

    palette_coeff_kernel<<<dim3(2), dim3(256), 0, stream>>>(palettes, temp, ws);
    palette_quant_kernel<<<dim3(NBLOCKS), dim3(THREADS), 0, stream>>>(
        images, ws, temp, out);
}